// Round 8
// baseline (225.524 us; speedup 1.0000x reference)
//
#include <hip/hip_runtime.h>

typedef int   int4v   __attribute__((ext_vector_type(4)));
typedef float float4v __attribute__((ext_vector_type(4)));

#define T_TOK 16384
#define HD    1024
#define IE    256
#define EN    8
#define VSZ   100000

// meta[] int indices
#define M_OFF 16   // [9] group offsets
#define M_TS1 25   // [9] gemm tile-start prefix (Mtile=32)

// ws byte offsets (all 16-aligned)
#define XQ_OFF   0ull           // T*1024 int8 (token-ordered)
#define PB1_OFF  21053440ull    // 8*64*512*16 int8 (gate|up packed)
#define PB2_OFF  25247744ull    // 8*16*1024*16 int8 (down packed)
#define PERM_OFF 27344896ull    // T int32
#define XS_OFF   27410688ull    // T float (token-ordered)
#define META_OFF 27542272ull    // 64 int32
#define BC_OFF   27542528ull    // 64*8 int32 per-block histograms
#define BB_OFF   27544576ull    // 64*8 int32 per-block bases

// async global->LDS, 16B per lane; LDS dest = wave-uniform base + lane*16
__device__ __forceinline__ void gload16(const void* g, void* l) {
    __builtin_amdgcn_global_load_lds(
        (const __attribute__((address_space(1))) unsigned int*)g,
        (__attribute__((address_space(3))) unsigned int*)l,
        16, 0, 0);
}

// per-block histogram -> bc[block][e]  (no global atomics)
__global__ void k_hist(const int* __restrict__ ids, const int* __restrict__ t2e,
                       int* __restrict__ bc) {
    __shared__ int h[EN];
    if (threadIdx.x < EN) h[threadIdx.x] = 0;
    __syncthreads();
    int t = blockIdx.x * 256 + threadIdx.x;
    int id = ids[t]; id = min(max(id, 0), VSZ - 1);
    atomicAdd(&h[t2e[id]], 1);
    __syncthreads();
    if (threadIdx.x < EN) bc[blockIdx.x * EN + threadIdx.x] = h[threadIdx.x];
}

// single block, 8 waves (one per expert): prefix over 64 blocks via shuffles
__global__ __launch_bounds__(512) void k_scan(const int* __restrict__ bc,
                                              int* __restrict__ bbase,
                                              int* __restrict__ meta) {
    int e = threadIdx.x >> 6;
    int b = threadIdx.x & 63;
    int c = bc[b * EN + e];
    int inc = c;
    #pragma unroll
    for (int s = 1; s < 64; s <<= 1) {
        int v = __shfl_up(inc, s, 64);
        if (b >= s) inc += v;
    }
    int exc = inc - c;
    __shared__ int tot[EN];
    __shared__ int goff[EN];
    if (b == 63) tot[e] = inc;
    __syncthreads();
    if (threadIdx.x == 0) {
        int off = 0, t1 = 0;
        meta[M_OFF] = 0; meta[M_TS1] = 0;
        #pragma unroll
        for (int i = 0; i < EN; ++i) {
            goff[i] = off;
            int cc = tot[i];
            off += cc; t1 += (cc + 31) >> 5;
            meta[M_OFF + i + 1] = off;
            meta[M_TS1 + i + 1] = t1;
        }
    }
    __syncthreads();
    bbase[b * EN + e] = goff[e] + exc;
}

// LDS cursors seeded from bbase -> zero global atomics
__global__ void k_assign(const int* __restrict__ ids, const int* __restrict__ t2e,
                         const int* __restrict__ bbase, int* __restrict__ perm) {
    __shared__ int cur[EN];
    if (threadIdx.x < EN) cur[threadIdx.x] = bbase[blockIdx.x * EN + threadIdx.x];
    __syncthreads();
    int t = blockIdx.x * 256 + threadIdx.x;
    int id = ids[t]; id = min(max(id, 0), VSZ - 1);
    int e = t2e[id];
    int slot = atomicAdd(&cur[e], 1);
    perm[slot] = t;
}

// ---------------------------------------------------------------------------
// k_pre: token-ordered activation quantization (blocks 0..4095, wave per token)
//        + weight repack into MFMA fragment layout (blocks 4096..5631).
// Fragment layout: elem(k,n) at ((k>>4)*N + n)*16 + (k&15)
// ---------------------------------------------------------------------------
__global__ __launch_bounds__(256) void k_pre(const float* __restrict__ hidden,
                                             const int* __restrict__ gq,
                                             const int* __restrict__ uq,
                                             const int* __restrict__ dq,
                                             signed char* __restrict__ xq,
                                             float* __restrict__ xs,
                                             signed char* __restrict__ pb1,
                                             signed char* __restrict__ pb2) {
    int b = blockIdx.x;
    if (b < 4096) {
        int w = threadIdx.x >> 6, lane = threadIdx.x & 63;
        int token = (b << 2) + w;
        const float* row = hidden + (size_t)token * HD;
        float v[16];
        #pragma unroll
        for (int j = 0; j < 4; ++j) {
            float4v f = *(const float4v*)(row + lane * 16 + j * 4);
            v[j*4+0] = f[0]; v[j*4+1] = f[1]; v[j*4+2] = f[2]; v[j*4+3] = f[3];
        }
        float mx = 0.0f;
        #pragma unroll
        for (int j = 0; j < 16; ++j) mx = fmaxf(mx, fabsf(v[j]));
        #pragma unroll
        for (int s = 1; s < 64; s <<= 1) mx = fmaxf(mx, __shfl_xor(mx, s, 64));
        float sc = fmaxf(mx / 127.0f, 1e-8f);
        if (lane == 0) xs[token] = sc;
        int4v pk;
        #pragma unroll
        for (int j = 0; j < 4; ++j) {
            int bb[4];
            #pragma unroll
            for (int u = 0; u < 4; ++u) {
                float t = rintf(v[j*4+u] / sc);           // round-half-even == jnp.round
                t = fminf(fmaxf(t, -128.0f), 127.0f);
                bb[u] = (int)t;
            }
            pk[j] = (bb[0] & 255) | ((bb[1] & 255) << 8) | ((bb[2] & 255) << 16) | (bb[3] << 24);
        }
        *(int4v*)(xq + (size_t)token * HD + lane * 16) = pk;
    } else {
        int idx = (b - 4096) * 256 + threadIdx.x;   // 0 .. 393215
        if (idx < 262144) {                          // gate|up fragments [8][64][512]
            int n = idx & 511, kc = (idx >> 9) & 63, e = idx >> 15;
            const int* src = (n < 256) ? gq + (((size_t)((e << 10) + (kc << 4)) << 8) + n)
                                       : uq + (((size_t)((e << 10) + (kc << 4)) << 8) + (n - 256));
            int4v pk;
            #pragma unroll
            for (int jj = 0; jj < 4; ++jj) {
                int b0 = src[(size_t)(jj * 4 + 0) << 8], b1 = src[(size_t)(jj * 4 + 1) << 8];
                int b2 = src[(size_t)(jj * 4 + 2) << 8], b3 = src[(size_t)(jj * 4 + 3) << 8];
                pk[jj] = (b0 & 255) | ((b1 & 255) << 8) | ((b2 & 255) << 16) | (b3 << 24);
            }
            *(int4v*)(pb1 + ((size_t)((((e << 6) + kc) << 9) + n) << 4)) = pk;
        } else {                                     // down fragments [8][16][1024]
            int j = idx - 262144;
            int n = j & 1023, kc = (j >> 10) & 15, e = j >> 14;
            const int* src = dq + (((size_t)((e << 8) + (kc << 4)) << 10) + n);
            int4v pk;
            #pragma unroll
            for (int jj = 0; jj < 4; ++jj) {
                int b0 = src[(size_t)(jj * 4 + 0) << 10], b1 = src[(size_t)(jj * 4 + 1) << 10];
                int b2 = src[(size_t)(jj * 4 + 2) << 10], b3 = src[(size_t)(jj * 4 + 3) << 10];
                pk[jj] = (b0 & 255) | ((b1 & 255) << 8) | ((b2 & 255) << 16) | (b3 << 24);
            }
            *(int4v*)(pb2 + ((size_t)((((e << 4) + kc) << 10) + n) << 4)) = pk;
        }
    }
}

// ---------------------------------------------------------------------------
// k_mlp: Mtile=32 fused MLP at 4 BLOCKS/CU (LDS 40960B exactly), SAFE-SYNC.
// 48 half-stages of 16KB (32 G1: granule g of K=64, h=0 gate / h=1 up cols;
// 16 G2: nh 512-col half, g2 K-granule, ch 256-col chunk).
// Schedule (round-2-proven, no hand vmcnt): per step
//   __syncthreads()   [drains stage s; WAR: buf (s+1)&1 readers done at s-1]
//   issue stage s+1 into lB[(s+1)&1]
//   compute stage s from lB[s&1]
// Stage s+1's latency hides under compute s + 4-block TLP (16 waves/CU).
// A operands direct-to-register per K-granule, parity-buffered.
// LDS: lB[2][16KB] + iqt 8KB (pmax/rsc overlaid, barrier-separated) = 40KB.
// Epilogue scalars (gs/us/xs/ds/tokr) deferred past phase 1 for VGPR<=128.
// Tile map: (blk%8)*65 + blk/8 -> 65 same-expert tiles per XCD (L2-resident
// weights; round 5 vs 6 proved 118MB vs 16MB FETCH). 520 tiles on 1024
// slots -> no tail round.
// ---------------------------------------------------------------------------
__global__ __launch_bounds__(256, 4) void k_mlp(const signed char* __restrict__ xq,
                                                const signed char* __restrict__ pb1,
                                                const signed char* __restrict__ pb2,
                                                const float* __restrict__ xs,
                                                const float* __restrict__ gsc,
                                                const float* __restrict__ usc,
                                                const float* __restrict__ dsc,
                                                const int* __restrict__ meta,
                                                const int* __restrict__ perm,
                                                float* __restrict__ out) {
    int b = (blockIdx.x & 7) * 65 + (blockIdx.x >> 3);   // XCD-contiguous tiles
    int e = -1, m0 = 0, gend = 0;
    #pragma unroll
    for (int i = 0; i < EN; ++i) {
        int s0 = meta[M_TS1 + i], s1 = meta[M_TS1 + i + 1];
        if (b >= s0 && b < s1) { e = i; m0 = meta[M_OFF + i] + ((b - s0) << 5); gend = meta[M_OFF + i + 1]; }
    }
    if (e < 0) return;   // block-uniform exit
    const int w = threadIdx.x >> 6, lane = threadIdx.x & 63;
    const int q = lane >> 4, r = lane & 15;

    __shared__ __align__(16) signed char lB[2][16384];
    __shared__ __align__(16) signed char iqt[8192];   // 32x256 swizzled int8
    float* pmax = (float*)iqt;          // [4][32], dead before iqt written
    float* rscp = (float*)(iqt + 512);  // [32],    dead before iqt written

    // A-row tokens: direct per-lane perm loads
    int tokA0 = perm[min(m0 + r, T_TOK - 1)];
    int tokA1 = perm[min(m0 + 16 + r, T_TOK - 1)];
    const signed char* aptr0 = xq + (size_t)tokA0 * HD + (q << 4);
    const signed char* aptr1 = xq + (size_t)tokA1 * HD + (q << 4);

    const signed char* pbe1 = pb1 + (size_t)e * (64 * 512 * 16);
    const signed char* pbe2 = pb2 + (size_t)e * (16 * 1024 * 16);

    // G1 half-stage: granule g (K=64, kc=4g+w), half h (0=gate cols,1=up cols)
    #define G1S(buf, g, h)                                                         \
        {                                                                          \
            const signed char* srow = pbe1 +                                       \
                (((size_t)((((g) << 2) + w) * 512 + ((h) << 8))) << 4);            \
            _Pragma("unroll")                                                      \
            for (int j = 0; j < 4; ++j) {                                          \
                int nx = ((j << 6) + lane) ^ ((w & 1) << 3);                       \
                gload16(srow + ((size_t)nx << 4), &lB[buf][((w << 2) + j) << 10]); \
            }                                                                      \
        }
    #define G1A(g)                                                                 \
        {                                                                          \
            areg[(g) & 1][0] = *(const int4v*)(aptr0 + ((g) << 6));                \
            areg[(g) & 1][1] = *(const int4v*)(aptr1 + ((g) << 6));                \
        }
    // G2 half-stage: st2 = nh*8 + g2*2 + ch  (kc=4*g2+w)
    #define G2S(buf, st2)                                                          \
        {                                                                          \
            int nh2 = (st2) >> 3, g22 = ((st2) >> 1) & 3, ch2 = (st2) & 1;         \
            const signed char* srow = pbe2 +                                       \
                (((size_t)(((g22 << 2) + w) * 1024 + (nh2 << 9) + (ch2 << 8))) << 4); \
            _Pragma("unroll")                                                      \
            for (int j = 0; j < 4; ++j) {                                          \
                int nx = ((j << 6) + lane) ^ ((w & 1) << 3);                       \
                gload16(srow + ((size_t)nx << 4), &lB[buf][((w << 2) + j) << 10]); \
            }                                                                      \
        }

    int4v zero = {0, 0, 0, 0};
    int4v accg[2][4], accu[2][4];
    #pragma unroll
    for (int mi = 0; mi < 2; ++mi)
        #pragma unroll
        for (int i = 0; i < 4; ++i) { accg[mi][i] = zero; accu[mi][i] = zero; }

    int4v areg[2][2];
    // prologue: stage 0 (gate g0) + A granule 0
    G1S(0, 0, 0);
    G1A(0);

    // ---------------- phase 1: gate|up GEMM, half-stages 0..31 ----------------
    #pragma unroll
    for (int s = 0; s < 32; ++s) {
        __syncthreads();                 // stage s (and A granule) arrived
        const int nxt = s + 1;
        if (nxt < 32) {
            G1S(nxt & 1, nxt >> 1, nxt & 1);
            if ((nxt & 1) == 0) G1A(nxt >> 1);
        }
        const int g = s >> 1, h = s & 1, cur = s & 1;
        int4v a0 = areg[g & 1][0], a1 = areg[g & 1][1];
        #pragma unroll
        for (int i = 0; i < 4; ++i) {
            int nl = (w << 6) + (i << 4) + r;
            int sl = (q << 8) + (nl ^ ((q & 1) << 3));
            int4v bb = *(const int4v*)&lB[cur][sl << 4];
            if (h == 0) {
                accg[0][i] = __builtin_amdgcn_mfma_i32_16x16x64_i8(a0, bb, accg[0][i], 0, 0, 0);
                accg[1][i] = __builtin_amdgcn_mfma_i32_16x16x64_i8(a1, bb, accg[1][i], 0, 0, 0);
            } else {
                accu[0][i] = __builtin_amdgcn_mfma_i32_16x16x64_i8(a0, bb, accu[0][i], 0, 0, 0);
                accu[1][i] = __builtin_amdgcn_mfma_i32_16x16x64_i8(a1, bb, accu[1][i], 0, 0, 0);
            }
        }
    }
    #undef G1S
    #undef G1A

    // issue first down-weight stage early; latency hides under the epilogue.
    // Safe: writes lB[0]; any wave still in compute s=31 reads lB[1].
    G2S(0, 0);

    // ------- epilogue: deferred scalars, silu*up, row max, requant -------
    int tokr[2][4];
    float xsr[2][4];
    #pragma unroll
    for (int mi = 0; mi < 2; ++mi)
        #pragma unroll
        for (int g2 = 0; g2 < 4; ++g2) {
            int slot = m0 + (mi << 4) + (q << 2) + g2;
            tokr[mi][g2] = perm[min(slot, T_TOK - 1)];
            xsr[mi][g2] = xs[tokr[mi][g2]];
        }
    float gs[4], us[4];
    #pragma unroll
    for (int i = 0; i < 4; ++i) {
        int n = (w << 6) + (i << 4) + r;
        gs[i] = gsc[e * IE + n];
        us[i] = usc[e * IE + n];
    }
    float ds[2][2][4];
    #pragma unroll
    for (int nh = 0; nh < 2; ++nh)
        #pragma unroll
        for (int ch = 0; ch < 2; ++ch)
            #pragma unroll
            for (int i = 0; i < 4; ++i)
                ds[nh][ch][i] = dsc[e * HD + (nh << 9) + (ch << 8) + (w << 6) + (i << 4) + r];

    float inter[2][4][4];
    float pm[2][4];
    #pragma unroll
    for (int mi = 0; mi < 2; ++mi)
        #pragma unroll
        for (int g2 = 0; g2 < 4; ++g2) {
            float mx = 0.0f;
            #pragma unroll
            for (int i = 0; i < 4; ++i) {
                float gv = (float)accg[mi][i][g2] * xsr[mi][g2] * gs[i];
                float uv = (float)accu[mi][i][g2] * xsr[mi][g2] * us[i];
                float sg = gv / (1.0f + expf(-gv));
                float vv = sg * uv;
                inter[mi][i][g2] = vv;
                mx = fmaxf(mx, fabsf(vv));
            }
            #pragma unroll
            for (int s = 1; s < 16; s <<= 1) mx = fmaxf(mx, __shfl_xor(mx, s, 64));
            pm[mi][g2] = mx;
        }

    if (r == 0) {
        #pragma unroll
        for (int mi = 0; mi < 2; ++mi)
            #pragma unroll
            for (int g2 = 0; g2 < 4; ++g2)
                pmax[(w << 5) + (mi << 4) + (q << 2) + g2] = pm[mi][g2];
    }
    __syncthreads();     // pmax published (and all waves past phase-1 lB reads)
    if (threadIdx.x < 32) {
        int row = threadIdx.x;
        float mx = fmaxf(fmaxf(pmax[row], pmax[32 + row]), fmaxf(pmax[64 + row], pmax[96 + row]));
        rscp[row] = fmaxf(mx / 127.0f, 1e-8f);
    }
    __syncthreads();     // rscp published
    float rscr[2][4];
    #pragma unroll
    for (int mi = 0; mi < 2; ++mi)
        #pragma unroll
        for (int g2 = 0; g2 < 4; ++g2)
            rscr[mi][g2] = rscp[(mi << 4) + (q << 2) + g2];
    __syncthreads();     // all pmax/rsc reads done -> safe to overwrite iqt region

    // quantize inter -> swizzled iqt tile (overwrites pmax/rsc area)
    #pragma unroll
    for (int mi = 0; mi < 2; ++mi)
        #pragma unroll
        for (int g2 = 0; g2 < 4; ++g2) {
            int row = (mi << 4) + (q << 2) + g2;
            float sc = rscr[mi][g2];
            #pragma unroll
            for (int i = 0; i < 4; ++i) {
                float t = rintf(inter[mi][i][g2] / sc);
                t = fminf(fmaxf(t, -128.0f), 127.0f);
                iqt[(row << 8) + ((((w << 2) + i) ^ (row & 3)) << 4) + r] = (signed char)(int)t;
            }
        }

    // ---------------- phase 3: down GEMM, half-stages 0..15 ----------------
    int4v acc2[2][2][4];   // [mi][ch][i]
    #pragma unroll
    for (int st = 0; st < 16; ++st) {
        __syncthreads();               // stage st arrived; iqt published (st=0)
        const int nxt2 = st + 1;
        if (nxt2 < 16) { G2S(nxt2 & 1, nxt2); }
        if ((st & 7) == 0) {
            #pragma unroll
            for (int mi = 0; mi < 2; ++mi)
                #pragma unroll
                for (int ch = 0; ch < 2; ++ch)
                    #pragma unroll
                    for (int i = 0; i < 4; ++i) acc2[mi][ch][i] = zero;
        }
        const int nh = st >> 3, g2v = (st >> 1) & 3, ch = st & 1, cur = st & 1;
        int4v a2[2];
        #pragma unroll
        for (int mi = 0; mi < 2; ++mi) {
            int row2 = (mi << 4) + r;
            a2[mi] = *(const int4v*)&iqt[(row2 << 8) + ((((g2v << 2) + q) ^ (r & 3)) << 4)];
        }
        #pragma unroll
        for (int i = 0; i < 4; ++i) {
            int nl = (w << 6) + (i << 4) + r;
            int sl = (q << 8) + (nl ^ ((q & 1) << 3));
            int4v bb = *(const int4v*)&lB[cur][sl << 4];
            acc2[0][ch][i] = __builtin_amdgcn_mfma_i32_16x16x64_i8(a2[0], bb, acc2[0][ch][i], 0, 0, 0);
            acc2[1][ch][i] = __builtin_amdgcn_mfma_i32_16x16x64_i8(a2[1], bb, acc2[1][ch][i], 0, 0, 0);
        }
        if ((st & 7) == 7) {
            #pragma unroll
            for (int mi = 0; mi < 2; ++mi)
                #pragma unroll
                for (int g2 = 0; g2 < 4; ++g2) {
                    int slot = m0 + (mi << 4) + (q << 2) + g2;
                    if (slot < gend) {
                        size_t ob = (size_t)tokr[mi][g2] * HD + (nh << 9) + (w << 6) + r;
                        #pragma unroll
                        for (int ch2 = 0; ch2 < 2; ++ch2)
                            #pragma unroll
                            for (int i = 0; i < 4; ++i)
                                out[ob + (ch2 << 8) + (i << 4)] =
                                    (float)acc2[mi][ch2][i][g2] * rscr[mi][g2] * ds[nh][ch2][i];
                    }
                }
        }
    }
    #undef G2S
}

extern "C" void kernel_launch(void* const* d_in, const int* in_sizes, int n_in,
                              void* d_out, int out_size, void* d_ws, size_t ws_size,
                              hipStream_t stream) {
    const float* hidden = (const float*)d_in[0];
    const int*   ids    = (const int*)d_in[1];
    const int*   gq     = (const int*)d_in[2];
    const float* gsc    = (const float*)d_in[3];
    const int*   uq     = (const int*)d_in[4];
    const float* usc    = (const float*)d_in[5];
    const int*   dq     = (const int*)d_in[6];
    const float* dsc    = (const float*)d_in[7];
    const int*   t2e    = (const int*)d_in[8];
    float* out = (float*)d_out;

    char* ws = (char*)d_ws;
    signed char* xq  = (signed char*)(ws + XQ_OFF);
    signed char* pb1 = (signed char*)(ws + PB1_OFF);
    signed char* pb2 = (signed char*)(ws + PB2_OFF);
    int*   perm = (int*)(ws + PERM_OFF);
    float* xs   = (float*)(ws + XS_OFF);
    int*   meta = (int*)(ws + META_OFF);
    int*   bc   = (int*)(ws + BC_OFF);
    int*   bbase= (int*)(ws + BB_OFF);

    k_hist<<<64, 256, 0, stream>>>(ids, t2e, bc);
    k_scan<<<1, 512, 0, stream>>>(bc, bbase, meta);
    k_assign<<<64, 256, 0, stream>>>(ids, t2e, bbase, perm);
    k_pre<<<5632, 256, 0, stream>>>(hidden, gq, uq, dq, xq, xs, pb1, pb2);
    k_mlp<<<520, 256, 0, stream>>>(xq, pb1, pb2, xs, gsc, usc, dsc, meta, perm, out);
}